// Round 1
// baseline (126.625 us; speedup 1.0000x reference)
//
#include <hip/hip_runtime.h>
#include <hip/hip_bf16.h>

typedef __attribute__((ext_vector_type(8))) __bf16 bf16x8;
typedef __attribute__((ext_vector_type(4))) float f32x4;

#define MFMA(a,b,c) __builtin_amdgcn_mfma_f32_16x16x32_bf16((a),(b),(c),0,0,0)

// LDS layout (64 KB total, static):
//  XB 0..16K   : x  [64][128] bf16 (swz) -> later ob [64][128] (attention out)
//  QB 16K..32K : q  [64][128] bf16 (swz) -> later pb heads 0,1 ([64][64] each)
//  KB 32K..48K : k  [64][128] bf16 (swz) -> later pb heads 2,3
//  VT 48K..64K : v^T [128][64] bf16 (swz)
#define XB 0u
#define QB 16384u
#define KB 32768u
#define VT 49152u

static __device__ __forceinline__ unsigned short f2u(float x) {
  return __builtin_bit_cast(unsigned short, static_cast<__bf16>(x));
}
static __device__ __forceinline__ unsigned long long pack4(float a, float b, float c, float d) {
  return (unsigned long long)f2u(a) | ((unsigned long long)f2u(b) << 16) |
         ((unsigned long long)f2u(c) << 32) | ((unsigned long long)f2u(d) << 48);
}
// swizzled byte offset inside a row-major bf16 tile; row stride 256B / 128B
static __device__ __forceinline__ unsigned sw256(unsigned row, unsigned colb) {
  return (row << 8) + (colb ^ ((row & 7u) << 4));
}
static __device__ __forceinline__ unsigned sw128(unsigned row, unsigned colb) {
  return (row << 7) + (colb ^ ((row & 7u) << 4));
}

// ---------------- prep: weights -> bf16, bias gather -> padded [4][64][64] ----------------
__global__ void rsa_prep(const float* __restrict__ qk_w, const float* __restrict__ v_w,
                         const float* __restrict__ proj_w, const float* __restrict__ bias_table,
                         unsigned short* __restrict__ wqk, unsigned short* __restrict__ wv,
                         unsigned short* __restrict__ wp, float* __restrict__ biasNN) {
  int t = blockIdx.x * blockDim.x + threadIdx.x;
  int stride = gridDim.x * blockDim.x;
  for (int i = t; i < 256 * 128; i += stride) wqk[i] = f2u(qk_w[i]);
  for (int i = t; i < 128 * 128; i += stride) wv[i] = f2u(v_w[i]);
  for (int i = t; i < 128 * 128; i += stride) wp[i] = f2u(proj_w[i]);
  for (int i = t; i < 4 * 64 * 64; i += stride) {
    int h = i >> 12, r = (i >> 6) & 63, m = i & 63;
    float v = -1e9f;
    if (r < 49 && m < 49) {
      int ri = r / 7, rj = r - ri * 7, mi = m / 7, mj = m - mi * 7;
      int rel = (ri - mi + 6) * 13 + (rj - mj + 6);
      v = bias_table[rel * 4 + h];
    }
    biasNN[i] = v;
  }
}

// ---------------- main: one window per block, 8 waves ----------------
__global__ __launch_bounds__(512, 4) void rsa_main(
    const float* __restrict__ x, const float* __restrict__ qk_bias,
    const float* __restrict__ v_bias, const float* __restrict__ proj_bias,
    const unsigned short* __restrict__ wqk, const unsigned short* __restrict__ wv,
    const unsigned short* __restrict__ wp, const float* __restrict__ biasNN,
    float* __restrict__ out) {
  __shared__ __align__(16) unsigned char LDS[65536];
  const int tid = threadIdx.x;
  const int w = tid >> 6;        // wave 0..7
  const int lane = tid & 63;
  const int c = lane & 15;       // fragment col/row index
  const int g = lane >> 4;       // k-group 0..3
  const int b = blockIdx.x;
  const float SCALE = 0.17677669529663687f;  // 32^-0.5

  // Phase 0: stage x (49x128 f32) -> bf16 LDS [64][128] swizzled, zero-pad rows 49..63
  {
    const f32x4* xp = reinterpret_cast<const f32x4*>(x + (size_t)b * 6272);
    for (int i = tid; i < 1568; i += 512) {
      f32x4 v = xp[i];
      unsigned row = (unsigned)i >> 5, c4 = (unsigned)i & 31;
      *reinterpret_cast<unsigned long long*>(LDS + XB + sw256(row, c4 * 8)) =
          pack4(v[0], v[1], v[2], v[3]);
    }
    for (int i = tid; i < 480; i += 512) {
      unsigned row = 49 + ((unsigned)i >> 5), c4 = (unsigned)i & 31;
      *reinterpret_cast<unsigned long long*>(LDS + XB + sw256(row, c4 * 8)) = 0ull;
    }
  }
  __syncthreads();

  // Phase 1a: [q;k]^T = Wqk @ X^T (output-transposed orientation).
  // Wave w does chout tiles {w, w+8}; mi=0 -> Q rows, mi=1 -> K rows.
#pragma unroll
  for (int mi = 0; mi < 2; ++mi) {
    const int mt = w + 8 * mi;  // chout tile 0..15 over 256 outputs
    bf16x8 a[4];
    const unsigned short* wrow = wqk + (mt * 16 + c) * 128 + g * 8;
#pragma unroll
    for (int ks = 0; ks < 4; ++ks) a[ks] = *reinterpret_cast<const bf16x8*>(wrow + ks * 32);
    const int chout = mt * 16 + g * 4;
    f32x4 bias4 = *reinterpret_cast<const f32x4*>(qk_bias + chout);
#pragma unroll
    for (int nt = 0; nt < 4; ++nt) {
      f32x4 acc = {0.f, 0.f, 0.f, 0.f};
#pragma unroll
      for (int ks = 0; ks < 4; ++ks) {
        bf16x8 bf = *reinterpret_cast<const bf16x8*>(LDS + XB + sw256(nt * 16 + c, (ks * 32 + g * 8) * 2));
        acc = MFMA(a[ks], bf, acc);
      }
      const unsigned tok = nt * 16 + c;
      const unsigned colb = ((mt & 7) * 16 + g * 4) * 2;
      float v0 = acc[0] + bias4[0], v1 = acc[1] + bias4[1];
      float v2 = acc[2] + bias4[2], v3 = acc[3] + bias4[3];
      if (mi == 0) { v0 *= SCALE; v1 *= SCALE; v2 *= SCALE; v3 *= SCALE; }
      const unsigned base = (mi == 0) ? QB : KB;
      *reinterpret_cast<unsigned long long*>(LDS + base + sw256(tok, colb)) = pack4(v0, v1, v2, v3);
    }
  }

  // Phase 1b: V = X @ Wv^T (normal orientation), stored transposed vtb[ch][tok]
  {
    const float vb = v_bias[w * 16 + c];
    bf16x8 bw[4];
    const unsigned short* wrow = wv + (w * 16 + c) * 128 + g * 8;
#pragma unroll
    for (int ks = 0; ks < 4; ++ks) bw[ks] = *reinterpret_cast<const bf16x8*>(wrow + ks * 32);
#pragma unroll
    for (int mt = 0; mt < 4; ++mt) {
      f32x4 acc = {0.f, 0.f, 0.f, 0.f};
#pragma unroll
      for (int ks = 0; ks < 4; ++ks) {
        bf16x8 af = *reinterpret_cast<const bf16x8*>(LDS + XB + sw256(mt * 16 + c, (ks * 32 + g * 8) * 2));
        acc = MFMA(af, bw[ks], acc);
      }
      const unsigned row = w * 16 + c;            // channel
      const unsigned colb = (mt * 16 + g * 4) * 2;  // token byte offset
      *reinterpret_cast<unsigned long long*>(LDS + VT + sw128(row, colb)) =
          pack4(acc[0] + vb, acc[1] + vb, acc[2] + vb, acc[3] + vb);
    }
  }
  __syncthreads();

  // Phase 2a: S^T = K @ Q^T per head (wave pair: h = w>>1, half = w&1 owns rt {2*half, 2*half+1})
  const int h = w >> 1;
  const int rt0 = (w & 1) * 2;
  f32x4 s[2][4];
#pragma unroll
  for (int r2 = 0; r2 < 2; ++r2) {
    const int rt = rt0 + r2;
    bf16x8 qf = *reinterpret_cast<const bf16x8*>(LDS + QB + sw256(rt * 16 + c, h * 64 + g * 16));
#pragma unroll
    for (int mt = 0; mt < 4; ++mt) {
      bf16x8 kf = *reinterpret_cast<const bf16x8*>(LDS + KB + sw256(mt * 16 + c, h * 64 + g * 16));
      f32x4 z = {0.f, 0.f, 0.f, 0.f};
      s[r2][mt] = MFMA(kf, qf, z);
    }
  }
  __syncthreads();  // q/k now dead; their LDS becomes pb

  // Phase 2b: softmax along m for each column r; write P row-major bf16 (pb aliases QB/KB)
  // Phase 2c: O^T = V^T @ P^T; write ob (aliases XB)
#pragma unroll
  for (int r2 = 0; r2 < 2; ++r2) {
    const int r = (rt0 + r2) * 16 + c;
    const float* bp = biasNN + ((h * 64 + r) << 6);
    float v[16];
#pragma unroll
    for (int mt = 0; mt < 4; ++mt) {
      f32x4 bb = *reinterpret_cast<const f32x4*>(bp + mt * 16 + g * 4);
#pragma unroll
      for (int j = 0; j < 4; ++j) v[mt * 4 + j] = s[r2][mt][j] + bb[j];
    }
    float mx = v[0];
#pragma unroll
    for (int j = 1; j < 16; ++j) mx = fmaxf(mx, v[j]);
    mx = fmaxf(mx, __shfl_xor(mx, 16));
    mx = fmaxf(mx, __shfl_xor(mx, 32));
    float sum = 0.f;
#pragma unroll
    for (int j = 0; j < 16; ++j) { v[j] = __expf(v[j] - mx); sum += v[j]; }
    sum += __shfl_xor(sum, 16);
    sum += __shfl_xor(sum, 32);
    const float inv = 1.0f / sum;
#pragma unroll
    for (int mt = 0; mt < 4; ++mt) {
      *reinterpret_cast<unsigned long long*>(LDS + QB + h * 8192 + sw128(r, (mt * 16 + g * 4) * 2)) =
          pack4(v[mt * 4] * inv, v[mt * 4 + 1] * inv, v[mt * 4 + 2] * inv, v[mt * 4 + 3] * inv);
    }
  }

#pragma unroll
  for (int dt = 0; dt < 2; ++dt) {
#pragma unroll
    for (int r2 = 0; r2 < 2; ++r2) {
      const int r = (rt0 + r2) * 16 + c;
      f32x4 acc = {0.f, 0.f, 0.f, 0.f};
#pragma unroll
      for (int ks = 0; ks < 2; ++ks) {
        bf16x8 af = *reinterpret_cast<const bf16x8*>(LDS + VT + sw128(h * 32 + dt * 16 + c, (ks * 32 + g * 8) * 2));
        bf16x8 pf = *reinterpret_cast<const bf16x8*>(LDS + QB + h * 8192 + sw128(r, (ks * 32 + g * 8) * 2));
        acc = MFMA(af, pf, acc);
      }
      const unsigned colb = (h * 32 + dt * 16 + g * 4) * 2;  // output channel bytes
      *reinterpret_cast<unsigned long long*>(LDS + XB + sw256(r, colb)) =
          pack4(acc[0], acc[1], acc[2], acc[3]);
    }
  }
  __syncthreads();

  // Phase 3: out^T = Wp @ O^T; f32x4 stores to global
  {
    bf16x8 ap[4];
    const unsigned short* wrow = wp + (w * 16 + c) * 128 + g * 8;
#pragma unroll
    for (int ks = 0; ks < 4; ++ks) ap[ks] = *reinterpret_cast<const bf16x8*>(wrow + ks * 32);
    f32x4 pb4 = *reinterpret_cast<const f32x4*>(proj_bias + w * 16 + g * 4);
#pragma unroll
    for (int nt = 0; nt < 4; ++nt) {
      f32x4 acc = {0.f, 0.f, 0.f, 0.f};
#pragma unroll
      for (int ks = 0; ks < 4; ++ks) {
        bf16x8 bf = *reinterpret_cast<const bf16x8*>(LDS + XB + sw256(nt * 16 + c, (ks * 32 + g * 8) * 2));
        acc = MFMA(ap[ks], bf, acc);
      }
      const int tok = nt * 16 + c;
      if (tok < 49) {
        f32x4 o = {acc[0] + pb4[0], acc[1] + pb4[1], acc[2] + pb4[2], acc[3] + pb4[3]};
        *reinterpret_cast<f32x4*>(out + ((size_t)b * 49 + tok) * 128 + w * 16 + g * 4) = o;
      }
    }
  }
}

extern "C" void kernel_launch(void* const* d_in, const int* in_sizes, int n_in,
                              void* d_out, int out_size, void* d_ws, size_t ws_size,
                              hipStream_t stream) {
  const float* x          = (const float*)d_in[0];
  const float* qk_w       = (const float*)d_in[1];
  const float* qk_b       = (const float*)d_in[2];
  const float* v_w        = (const float*)d_in[3];
  const float* v_b        = (const float*)d_in[4];
  const float* proj_w     = (const float*)d_in[5];
  const float* proj_b     = (const float*)d_in[6];
  const float* bias_table = (const float*)d_in[7];
  float* out = (float*)d_out;

  // workspace carve (196608 B): wqk bf16 [256*128] | wv [128*128] | wp [128*128] | biasNN f32 [4*64*64]
  unsigned short* wqk = (unsigned short*)d_ws;
  unsigned short* wv  = wqk + 256 * 128;
  unsigned short* wp  = wv + 128 * 128;
  float* biasNN = (float*)((char*)d_ws + 131072);

  const int B = in_sizes[0] / (49 * 128);

  rsa_prep<<<dim3(128), dim3(512), 0, stream>>>(qk_w, v_w, proj_w, bias_table, wqk, wv, wp, biasNN);
  rsa_main<<<dim3(B), dim3(512), 0, stream>>>(x, qk_b, v_b, proj_b, wqk, wv, wp, biasNN, out);
}